// Round 10
// baseline (642.226 us; speedup 1.0000x reference)
//
#include <hip/hip_runtime.h>
#include <hip/hip_bf16.h>
#include <math.h>

// ---------------------------------------------------------------------------
// MoE block: y = sum_topk2 w_e * FFN_e(x)  +  FFN_shared(x)
// T=4096, D=1024, H=4096, E=8, K=2.  bf16 MFMA compute.
// R10: faithful m201-style 8-phase 256x256 GEMM. 8 waves (2Mx4N), BK=64,
// LDS = 2 slots x 2 halves x [128][64] x {A,B} = 128 KB. Per phase:
// {ds_read subtile || stage ONE half-tile || [ph4/8: vmcnt(4)] -> s_barrier
// -> lgkmcnt(0)+sched_barrier -> setprio 16xMFMA -> s_barrier}. Stage stream
// per iter (tiles 2i,2i+1): t1.A0,t1.A1,t2.B0,t2.B1,t2.A0,t2.A1,t3.B0,t3.B1
// (each write >=1 phase after its slot's last read-barrier; vmcnt(4) at
// ph4/ph8 drains exactly the next tile).
// ---------------------------------------------------------------------------

typedef unsigned short ushort_t;
typedef __attribute__((ext_vector_type(8))) __bf16 bf16x8;
typedef __attribute__((ext_vector_type(4))) float f32x4;

#define T_TOK 4096
#define DDIM  1024
#define HDIM  4096
#define NEXP  8
#define SLOT_PAD 10240           // 8192 + 8*256 pad headroom (256-aligned regions)
#define M_ALL (SLOT_PAD + T_TOK) // 14336 rows: experts then shared

// workspace layout (bytes)
#define OFF_CNT   0u             // int[8] cnt + int[8] cur
#define OFF_OFFS  64u            // int[16]
#define OFF_TIDX  256u           // int[8192]
#define OFF_TW    33024u         // float[8192]
#define OFF_SLOT  65792u         // int[8192]
#define OFF_TOK   98560u         // int[10240]
#define OFF_XALL  1048576u                        // bf16 [14336][1024] = 29,360,128
#define OFF_OUTS  OFF_XALL                        // bf16 [10240][1024] (aliases Xall)
#define OFF_WT    (OFF_XALL + 29360128u)          // bf16 [9][N][K] = 75,497,472
#define OFF_H     (OFF_WT + 75497472u)            // bf16 [14336][4096] = 117,440,512

__device__ __forceinline__ ushort_t f2b(float f) {
    __hip_bfloat16 h = __float2bfloat16(f);
    return *reinterpret_cast<ushort_t*>(&h);
}
__device__ __forceinline__ float b2f(ushort_t u) {
    __hip_bfloat16 h;
    *reinterpret_cast<ushort_t*>(&h) = u;
    return __bfloat162float(h);
}
// tanh-form GELU (max |dev| from exact erf-GELU ~3e-3; bf16-safe here)
__device__ __forceinline__ float gelu_fast(float v) {
    float u = 0.7978845608f * v * (1.0f + 0.044715f * v * v);
    float t = 1.0f - 2.0f / (__expf(2.0f * u) + 1.0f);
    return 0.5f * v * (1.0f + t);
}

// -------------------------------- init -------------------------------------
__global__ void init_kernel(int* __restrict__ cnt, int* __restrict__ tok_of) {
    int i = blockIdx.x * 256 + threadIdx.x;
    if (i < 16) cnt[i] = 0;
    if (i < SLOT_PAD) tok_of[i] = -1;
}

// -------------------------------- gate -------------------------------------
__global__ void gate_kernel(const float* __restrict__ x, const float* __restrict__ gw,
                            int* __restrict__ tidx, float* __restrict__ tw,
                            int* __restrict__ cnt) {
    int t = blockIdx.x;
    int l = threadIdx.x;
    float acc[NEXP];
#pragma unroll
    for (int e = 0; e < NEXP; ++e) acc[e] = 0.f;
    for (int i = 0; i < DDIM / 64; ++i) {
        float xi = x[(size_t)t * DDIM + i * 64 + l];
#pragma unroll
        for (int e = 0; e < NEXP; ++e)
            acc[e] += xi * gw[e * DDIM + i * 64 + l];
    }
#pragma unroll
    for (int e = 0; e < NEXP; ++e)
        for (int off = 32; off; off >>= 1) acc[e] += __shfl_xor(acc[e], off);
    if (l == 0) {
        float m = acc[0];
#pragma unroll
        for (int e = 1; e < NEXP; ++e) m = fmaxf(m, acc[e]);
        float ex[NEXP], Z = 0.f;
#pragma unroll
        for (int e = 0; e < NEXP; ++e) { ex[e] = __expf(acc[e] - m); Z += ex[e]; }
        int b0 = 0;
#pragma unroll
        for (int e = 1; e < NEXP; ++e) if (ex[e] > ex[b0]) b0 = e;
        int b1 = (b0 == 0) ? 1 : 0;
#pragma unroll
        for (int e = 0; e < NEXP; ++e) if (e != b0 && ex[e] > ex[b1]) b1 = e;
        float inv = 1.0f / Z;
        tidx[2 * t] = b0; tidx[2 * t + 1] = b1;
        tw[2 * t] = ex[b0] * inv; tw[2 * t + 1] = ex[b1] * inv;
        atomicAdd(&cnt[b0], 1);
        atomicAdd(&cnt[b1], 1);
    }
}

// ------------------------------ offsets ------------------------------------
__global__ void offs_kernel(const int* __restrict__ cnt, int* __restrict__ offs) {
    if (threadIdx.x == 0 && blockIdx.x == 0) {
        int o = 0;
#pragma unroll
        for (int e = 0; e < NEXP; ++e) {
            offs[e] = o;
            o += (cnt[e] + 255) & ~255;
        }
        offs[NEXP] = o;
    }
}

// ------------------------------- assign ------------------------------------
// slot order within an expert is atomic-race-dependent, but the OUTPUT is
// permutation-invariant (each slot row computed independently).
__global__ void assign_kernel(const int* __restrict__ tidx, const int* __restrict__ offs,
                              int* __restrict__ cur, int* __restrict__ slot_of,
                              int* __restrict__ tok_of) {
    int i = blockIdx.x * 256 + threadIdx.x;
    if (i >= 2 * T_TOK) return;
    int e = tidx[i];
    int s = offs[e] + atomicAdd(&cur[e], 1);
    slot_of[i] = s;
    tok_of[s] = i >> 1;
}

// ------------------------------- build X -----------------------------------
__global__ void build_x(const float* __restrict__ x, const int* __restrict__ tok_of,
                        const int* __restrict__ offs, ushort_t* __restrict__ Xall) {
    int b = blockIdx.x;
    int k = threadIdx.x * 4;
    int t;
    if (b < SLOT_PAD) {
        if (b >= offs[NEXP]) return;
        t = tok_of[b];
    } else {
        t = b - SLOT_PAD;
    }
    float4 v = make_float4(0.f, 0.f, 0.f, 0.f);
    if (t >= 0) v = *(const float4*)(x + (size_t)t * DDIM + k);
    ushort_t* p = Xall + (size_t)b * DDIM + k;
    p[0] = f2b(v.x); p[1] = f2b(v.y); p[2] = f2b(v.z); p[3] = f2b(v.w);
}

// --------------------------- transpose + cvt -------------------------------
// in [K][N] fp32 -> out [N][K] bf16 ; grid (K/64, N/64, batch)
__global__ void transpose_cvt(const float* __restrict__ in, ushort_t* __restrict__ out,
                              int K, int N) {
    __shared__ float t[64][65];
    size_t zoff = (size_t)blockIdx.z * K * N;
    in += zoff; out += zoff;
    int k0 = blockIdx.x * 64, n0 = blockIdx.y * 64;
    int c = threadIdx.x & 63, r4 = threadIdx.x >> 6;
#pragma unroll
    for (int i = 0; i < 16; ++i) {
        int r = r4 + i * 4;
        t[r][c] = in[(size_t)(k0 + r) * N + n0 + c];
    }
    __syncthreads();
#pragma unroll
    for (int i = 0; i < 16; ++i) {
        int r = r4 + i * 4;
        out[(size_t)(n0 + r) * K + k0 + c] = f2b(t[c][r]);
    }
}

// --------------------- GEMM 256x256 8-phase (m201 port) --------------------
// C[M,N] = act(A[M,K] @ Bt[e][N,K]^T + bias), rows grouped by expert
// (256-aligned), expert 8 = shared. 512 thr / 8 waves (2M x 4N), wave out
// 128x64 (acc[8][4]). LDS As/Bs[2 slot][2 half][128*64] = 128 KB.
// Per K-tile: 4 phases, phase q computes M-frags {2q,2q+1} x 4 N-frags x
// 2 ksteps = 16 MFMA; B-frags (8 reads) loaded once at q=0 and held.
// Chunk-XOR swizzle c=(chunk)^(row&7), pre-swizzled global source (0
// conflicts measured R2-R9). vmcnt(4) only at phases 4/8 of each iteration.
#define PHASE(SLOT, Q, STAGE, WAIT)                                          \
    {                                                                        \
        const ushort_t* Ah = &As[SLOT][wm][0];                               \
        const ushort_t* Bh = &Bs[SLOT][wn >> 1][0];                          \
        if ((Q) == 0) {                                                      \
            _Pragma("unroll") for (int nf = 0; nf < 4; ++nf)                 \
            _Pragma("unroll") for (int ks = 0; ks < 2; ++ks) {               \
                int r = (wn & 1) * 64 + nf * 16 + lr;                        \
                int c = ((ks << 2) + q4) ^ (r & 7);                          \
                bfr[nf][ks] = *(const bf16x8*)(Bh + r * 64 + c * 8);         \
            }                                                                \
        }                                                                    \
        bf16x8 af[2][2];                                                     \
        _Pragma("unroll") for (int d = 0; d < 2; ++d)                        \
        _Pragma("unroll") for (int ks = 0; ks < 2; ++ks) {                   \
            int r = (2 * (Q) + d) * 16 + lr;                                 \
            int c = ((ks << 2) + q4) ^ (r & 7);                              \
            af[d][ks] = *(const bf16x8*)(Ah + r * 64 + c * 8);               \
        }                                                                    \
        STAGE;                                                               \
        if (WAIT) asm volatile("s_waitcnt vmcnt(4)" ::: "memory");           \
        __builtin_amdgcn_s_barrier();                                        \
        asm volatile("s_waitcnt lgkmcnt(0)" ::: "memory");                   \
        __builtin_amdgcn_sched_barrier(0);                                   \
        __builtin_amdgcn_s_setprio(1);                                       \
        _Pragma("unroll") for (int d = 0; d < 2; ++d)                        \
        _Pragma("unroll") for (int nf = 0; nf < 4; ++nf)                     \
        _Pragma("unroll") for (int ks = 0; ks < 2; ++ks)                     \
            acc[2 * (Q) + d][nf] = __builtin_amdgcn_mfma_f32_16x16x32_bf16(  \
                af[d][ks], bfr[nf][ks], acc[2 * (Q) + d][nf], 0, 0, 0);      \
        __builtin_amdgcn_s_setprio(0);                                       \
        __builtin_amdgcn_s_barrier();                                        \
    }

template <bool ACT_GELU, bool FFN2>
__global__ __launch_bounds__(512, 2) void gemm_moe(
    const ushort_t* __restrict__ A, const ushort_t* __restrict__ WtBase,
    const float* __restrict__ bExp, const float* __restrict__ bSh,
    ushort_t* __restrict__ Cb, float* __restrict__ Cf,
    const int* __restrict__ offs, int N, int K) {
    // ---- per-XCD patch swizzle (bijective; NM%4==0, NN%2==0) ----
    int NMt = gridDim.x, NNt = gridDim.y;
    int flat = blockIdx.y * NMt + blockIdx.x;
    int xcd = flat & 7, rank = flat >> 3;
    int PM = NMt >> 2;                    // patch rows (14)
    int PN = NNt >> 1;                    // patch cols (8 or 2)
    int pm = xcd >> 1, pn = xcd & 1;      // 4 x 2 patch grid
    int mi = pm * PM + rank / PN;
    int ni = pn * PN + rank % PN;
    int m0 = mi * 256, n0 = ni * 256;

    int e;
    if (m0 >= SLOT_PAD) {
        e = NEXP;                        // shared region
    } else {
        if (m0 >= offs[NEXP]) return;    // dead pad zone (before any barrier)
        e = 0;
        while (offs[e + 1] <= m0) e++;
    }
    const ushort_t* Bt = WtBase + (size_t)e * N * K;
    const float* bias = (e == NEXP) ? bSh : bExp + (size_t)e * N;

    __shared__ ushort_t As[2][2][128 * 64];   // [slot][half] 64 KB
    __shared__ ushort_t Bs[2][2][128 * 64];   // 64 KB

    int tid = threadIdx.x;
    int lane = tid & 63, wid = tid >> 6;   // 8 waves
    int wm = wid >> 2, wn = wid & 3;       // 2M x 4N wave grid
    int q4 = lane >> 4, lr = lane & 15;

    // ---- staging addressing: one half-tile = [128][64] = 1024 chunks of
    // 16 B; thread covers L = it*512 + tid (it=0,1). row=L>>3, stored
    // chunk=L&7, source chunk = (L&7)^(row&7) (pre-swizzled source).
    int srow = tid >> 3;                       // 0..63 (it adds 64; &7 same)
    int sc = ((tid & 7) ^ (srow & 7)) * 8;     // source element offset
    size_t aB[2][2], bB[2][2];
    int ldsI[2];
#pragma unroll
    for (int h = 0; h < 2; ++h)
#pragma unroll
        for (int it = 0; it < 2; ++it) {
            aB[h][it] = (size_t)(m0 + h * 128 + it * 64 + srow) * K + sc;
            bB[h][it] = (size_t)(n0 + h * 128 + it * 64 + srow) * K + sc;
        }
#pragma unroll
    for (int it = 0; it < 2; ++it) ldsI[it] = (it * 512 + tid) * 8;

    auto stA = [&](int kb, int slot, int h) {   // stage one A half-tile
#pragma unroll
        for (int it = 0; it < 2; ++it)
            __builtin_amdgcn_global_load_lds(
                (const __attribute__((address_space(1))) void*)(A + aB[h][it] + kb),
                (__attribute__((address_space(3))) void*)(&As[slot][h][ldsI[it]]),
                16, 0, 0);
    };
    auto stB = [&](int kb, int slot, int h) {   // stage one B half-tile
#pragma unroll
        for (int it = 0; it < 2; ++it)
            __builtin_amdgcn_global_load_lds(
                (const __attribute__((address_space(1))) void*)(Bt + bB[h][it] + kb),
                (__attribute__((address_space(3))) void*)(&Bs[slot][h][ldsI[it]]),
                16, 0, 0);
    };

    f32x4 acc[8][4];
#pragma unroll
    for (int i = 0; i < 8; ++i)
#pragma unroll
        for (int j = 0; j < 4; ++j) acc[i][j] = (f32x4)(0.f);

    const int nk = K >> 6;                 // 16 or 64 K-tiles
    const int nk2 = nk >> 1;               // iterations (2 K-tiles each)

    // ---- prologue: tile0 full + tile1 B-halves; vmcnt(4) drains tile0 ----
    stB(0, 0, 0); stB(0, 0, 1);
    stA(0, 0, 0); stA(0, 0, 1);
    stB(64, 1, 0); stB(64, 1, 1);
    asm volatile("s_waitcnt vmcnt(4)" ::: "memory");
    __builtin_amdgcn_s_barrier();

    for (int i = 0; i < nk2; ++i) {
        int t1 = 2 * i + 1;                // < nk always
        int t2 = 2 * i + 2; if (t2 >= nk) t2 -= nk;   // wrap tail
        int t3 = 2 * i + 3; if (t3 >= nk) t3 -= nk;
        int k1 = t1 << 6, k2 = t2 << 6, k3 = t3 << 6;
        bf16x8 bfr[4][2];                  // B-frags held per K-tile

        // K-tile 2i from slot 0 (phases 1-4)
        PHASE(0, 0, stA(k1, 1, 0), false)
        PHASE(0, 1, stA(k1, 1, 1), false)
        PHASE(0, 2, stB(k2, 0, 0), false)
        PHASE(0, 3, stB(k2, 0, 1), true)   // vmcnt(4): tile 2i+1 landed
        // K-tile 2i+1 from slot 1 (phases 5-8)
        PHASE(1, 0, stA(k2, 0, 0), false)
        PHASE(1, 1, stA(k2, 0, 1), false)
        PHASE(1, 2, stB(k3, 1, 0), false)
        PHASE(1, 3, stB(k3, 1, 1), true)   // vmcnt(4): tile 2i+2 landed
    }
    asm volatile("s_waitcnt vmcnt(0)" ::: "memory");  // drain wrap stages

    // epilogue: C/D map col=lane&15, row=(lane>>4)*4+reg
    int colb = n0 + wn * 64 + lr;
    int rowb = m0 + wm * 128 + q4 * 4;
#pragma unroll
    for (int nf = 0; nf < 4; ++nf) {
        int col = colb + nf * 16;
        float bz = bias[col];
#pragma unroll
        for (int mf = 0; mf < 8; ++mf) {
            int row = rowb + mf * 16;
#pragma unroll
            for (int r = 0; r < 4; ++r) {
                float v = acc[mf][nf][r] + bz;
                if (ACT_GELU) v = gelu_fast(v);
                if (!FFN2 || e < NEXP)
                    Cb[(size_t)(row + r) * N + col] = f2b(v);
                else
                    Cf[(size_t)(row + r - SLOT_PAD) * N + col] = v;
            }
        }
    }
}

// ------------------------------- combine -----------------------------------
__global__ void combine_kernel(float* __restrict__ out, const ushort_t* __restrict__ OutS,
                               const int* __restrict__ slot_of, const float* __restrict__ tw) {
    int t = blockIdx.x;
    int d = threadIdx.x * 4;
    int s0 = slot_of[2 * t], s1 = slot_of[2 * t + 1];
    float w0 = tw[2 * t], w1 = tw[2 * t + 1];
    float* po = out + (size_t)t * DDIM + d;
    float4 o = *(float4*)po;
    const ushort_t* p0 = OutS + (size_t)s0 * DDIM + d;
    const ushort_t* p1 = OutS + (size_t)s1 * DDIM + d;
    o.x += w0 * b2f(p0[0]) + w1 * b2f(p1[0]);
    o.y += w0 * b2f(p0[1]) + w1 * b2f(p1[1]);
    o.z += w0 * b2f(p0[2]) + w1 * b2f(p1[2]);
    o.w += w0 * b2f(p0[3]) + w1 * b2f(p1[3]);
    *(float4*)po = o;
}

// ------------------------------- launch ------------------------------------
extern "C" void kernel_launch(void* const* d_in, const int* in_sizes, int n_in,
                              void* d_out, int out_size, void* d_ws, size_t ws_size,
                              hipStream_t stream) {
    const float* x      = (const float*)d_in[0];
    const float* gw     = (const float*)d_in[1];
    const float* w_in   = (const float*)d_in[2];
    const float* b_in   = (const float*)d_in[3];
    const float* w_out  = (const float*)d_in[4];
    const float* b_out  = (const float*)d_in[5];
    const float* sw_in  = (const float*)d_in[6];
    const float* sb_in  = (const float*)d_in[7];
    const float* sw_out = (const float*)d_in[8];
    const float* sb_out = (const float*)d_in[9];
    float* out = (float*)d_out;

    char* ws = (char*)d_ws;
    int*      cnt     = (int*)(ws + OFF_CNT);      // [0..7]=cnt, [8..15]=cur
    int*      offs    = (int*)(ws + OFF_OFFS);
    int*      tidx    = (int*)(ws + OFF_TIDX);
    float*    tw      = (float*)(ws + OFF_TW);
    int*      slot_of = (int*)(ws + OFF_SLOT);
    int*      tok_of  = (int*)(ws + OFF_TOK);
    ushort_t* Xall    = (ushort_t*)(ws + OFF_XALL);
    ushort_t* OutS    = (ushort_t*)(ws + OFF_OUTS); // aliases Xall (used after GEMM1)
    ushort_t* Wt      = (ushort_t*)(ws + OFF_WT);   // [9][N][K], FFN1 then FFN2
    ushort_t* Hbuf    = (ushort_t*)(ws + OFF_H);    // bf16 [14336][4096]

    // routing
    init_kernel<<<(SLOT_PAD + 255) / 256, 256, 0, stream>>>(cnt, tok_of);
    gate_kernel<<<T_TOK, 64, 0, stream>>>(x, gw, tidx, tw, cnt);
    offs_kernel<<<1, 64, 0, stream>>>(cnt, offs);
    assign_kernel<<<(2 * T_TOK + 255) / 256, 256, 0, stream>>>(tidx, offs, cnt + 8,
                                                               slot_of, tok_of);
    build_x<<<M_ALL, 256, 0, stream>>>(x, tok_of, offs, Xall);

    // FFN1 weights: [9][4096][1024] bf16  (w_in experts + sw_in as expert 8)
    transpose_cvt<<<dim3(DDIM / 64, HDIM / 64, NEXP), 256, 0, stream>>>(w_in, Wt, DDIM, HDIM);
    transpose_cvt<<<dim3(DDIM / 64, HDIM / 64, 1), 256, 0, stream>>>(
        sw_in, Wt + (size_t)NEXP * HDIM * DDIM, DDIM, HDIM);
    // H = gelu(Xall @ W1 + b1)
    gemm_moe<true, false><<<dim3(M_ALL / 256, HDIM / 256), 512, 0, stream>>>(
        Xall, Wt, b_in, sb_in, Hbuf, nullptr, offs, HDIM, DDIM);

    // FFN2 weights: [9][1024][4096] bf16
    transpose_cvt<<<dim3(HDIM / 64, DDIM / 64, NEXP), 256, 0, stream>>>(w_out, Wt, HDIM, DDIM);
    transpose_cvt<<<dim3(HDIM / 64, DDIM / 64, 1), 256, 0, stream>>>(
        sw_out, Wt + (size_t)NEXP * HDIM * DDIM, HDIM, DDIM);
    // expert rows -> OutS (bf16); shared rows -> out (fp32, includes bias)
    gemm_moe<false, true><<<dim3(M_ALL / 256, DDIM / 256), 512, 0, stream>>>(
        Hbuf, Wt, b_out, sb_out, OutS, out, offs, DDIM, HDIM);

    // out += w0*OutS[slot0] + w1*OutS[slot1]
    combine_kernel<<<T_TOK, 256, 0, stream>>>(out, OutS, slot_of, tw);
    (void)in_sizes; (void)n_in; (void)out_size; (void)ws_size;
}

// Round 11
// 554.380 us; speedup vs baseline: 1.1585x; 1.1585x over previous
//
#include <hip/hip_runtime.h>
#include <hip/hip_bf16.h>
#include <math.h>

// ---------------------------------------------------------------------------
// MoE block: y = sum_topk2 w_e * FFN_e(x)  +  FFN_shared(x)
// T=4096, D=1024, H=4096, E=8, K=2.  bf16 MFMA compute.
// R11: R8 GEMM base (256x256, 16 waves, 2-phase dbuf + counted vmcnt — the
// measured-best schedule) with swapped-operand MFMA so the epilogue stores
// are vectorized (uint2/float4, 4x fewer store instrs), plus launch
// consolidation: memsetAsync cnt, offs folded into assign, pad detection
// from cnt (no tok_of pre-init), 9-expert batched transposes.
// ---------------------------------------------------------------------------

typedef unsigned short ushort_t;
typedef __attribute__((ext_vector_type(8))) __bf16 bf16x8;
typedef __attribute__((ext_vector_type(4))) float f32x4;

#define T_TOK 4096
#define DDIM  1024
#define HDIM  4096
#define NEXP  8
#define SLOT_PAD 10240           // 8192 + 8*256 pad headroom (256-aligned regions)
#define M_ALL (SLOT_PAD + T_TOK) // 14336 rows: experts then shared

// workspace layout (bytes)
#define OFF_CNT   0u             // int[8] cnt + int[8] cur
#define OFF_OFFS  64u            // int[16]
#define OFF_TIDX  256u           // int[8192]
#define OFF_TW    33024u         // float[8192]
#define OFF_SLOT  65792u         // int[8192]
#define OFF_TOK   98560u         // int[10240]
#define OFF_XALL  1048576u                        // bf16 [14336][1024] = 29,360,128
#define OFF_OUTS  OFF_XALL                        // bf16 [10240][1024] (aliases Xall)
#define OFF_WT    (OFF_XALL + 29360128u)          // bf16 [9][N][K] = 75,497,472
#define OFF_H     (OFF_WT + 75497472u)            // bf16 [14336][4096] = 117,440,512

__device__ __forceinline__ ushort_t f2b(float f) {
    __hip_bfloat16 h = __float2bfloat16(f);
    return *reinterpret_cast<ushort_t*>(&h);
}
__device__ __forceinline__ float b2f(ushort_t u) {
    __hip_bfloat16 h;
    *reinterpret_cast<ushort_t*>(&h) = u;
    return __bfloat162float(h);
}
// tanh-form GELU (max |dev| from exact erf-GELU ~3e-3; bf16-safe here)
__device__ __forceinline__ float gelu_fast(float v) {
    float u = 0.7978845608f * v * (1.0f + 0.044715f * v * v);
    float t = 1.0f - 2.0f / (__expf(2.0f * u) + 1.0f);
    return 0.5f * v * (1.0f + t);
}

// -------------------------------- gate -------------------------------------
__global__ void gate_kernel(const float* __restrict__ x, const float* __restrict__ gw,
                            int* __restrict__ tidx, float* __restrict__ tw,
                            int* __restrict__ cnt) {
    int t = blockIdx.x;
    int l = threadIdx.x;
    float acc[NEXP];
#pragma unroll
    for (int e = 0; e < NEXP; ++e) acc[e] = 0.f;
    for (int i = 0; i < DDIM / 64; ++i) {
        float xi = x[(size_t)t * DDIM + i * 64 + l];
#pragma unroll
        for (int e = 0; e < NEXP; ++e)
            acc[e] += xi * gw[e * DDIM + i * 64 + l];
    }
#pragma unroll
    for (int e = 0; e < NEXP; ++e)
        for (int off = 32; off; off >>= 1) acc[e] += __shfl_xor(acc[e], off);
    if (l == 0) {
        float m = acc[0];
#pragma unroll
        for (int e = 1; e < NEXP; ++e) m = fmaxf(m, acc[e]);
        float ex[NEXP], Z = 0.f;
#pragma unroll
        for (int e = 0; e < NEXP; ++e) { ex[e] = __expf(acc[e] - m); Z += ex[e]; }
        int b0 = 0;
#pragma unroll
        for (int e = 1; e < NEXP; ++e) if (ex[e] > ex[b0]) b0 = e;
        int b1 = (b0 == 0) ? 1 : 0;
#pragma unroll
        for (int e = 0; e < NEXP; ++e) if (e != b0 && ex[e] > ex[b1]) b1 = e;
        float inv = 1.0f / Z;
        tidx[2 * t] = b0; tidx[2 * t + 1] = b1;
        tw[2 * t] = ex[b0] * inv; tw[2 * t + 1] = ex[b1] * inv;
        atomicAdd(&cnt[b0], 1);
        atomicAdd(&cnt[b1], 1);
    }
}

// ------------------------- assign (+ offs, merged) -------------------------
// Every block recomputes the 8-entry padded prefix from cnt (reads only);
// block 0 thread 0 publishes offs. Slot order within an expert is
// atomic-race-dependent, but the OUTPUT is permutation-invariant.
__global__ void assign_kernel(const int* __restrict__ tidx, const int* __restrict__ cnt,
                              int* __restrict__ cur, int* __restrict__ offs,
                              int* __restrict__ slot_of, int* __restrict__ tok_of) {
    int off[NEXP + 1];
    off[0] = 0;
#pragma unroll
    for (int e = 0; e < NEXP; ++e) off[e + 1] = off[e] + ((cnt[e] + 255) & ~255);
    int i = blockIdx.x * 256 + threadIdx.x;
    if (i == 0) {
#pragma unroll
        for (int e = 0; e <= NEXP; ++e) offs[e] = off[e];
    }
    if (i >= 2 * T_TOK) return;
    int e = tidx[i];
    int s = off[e] + atomicAdd(&cur[e], 1);
    slot_of[i] = s;
    tok_of[s] = i >> 1;
}

// ------------------------------- build X -----------------------------------
// Pad slots detected from offs+cnt (local index >= cnt[e]) — no tok_of init.
__global__ void build_x(const float* __restrict__ x, const int* __restrict__ tok_of,
                        const int* __restrict__ offs, const int* __restrict__ cnt,
                        ushort_t* __restrict__ Xall) {
    int b = blockIdx.x;
    int k = threadIdx.x * 4;
    int t;
    if (b < SLOT_PAD) {
        if (b >= offs[NEXP]) return;
        int e = 0;
        while (offs[e + 1] <= b) e++;
        t = (b - offs[e] < cnt[e]) ? tok_of[b] : -1;
    } else {
        t = b - SLOT_PAD;
    }
    float4 v = make_float4(0.f, 0.f, 0.f, 0.f);
    if (t >= 0) v = *(const float4*)(x + (size_t)t * DDIM + k);
    ushort_t* p = Xall + (size_t)b * DDIM + k;
    p[0] = f2b(v.x); p[1] = f2b(v.y); p[2] = f2b(v.z); p[3] = f2b(v.w);
}

// --------------------------- transpose + cvt (9 experts) -------------------
// in [K][N] fp32 -> out [N][K] bf16 ; grid (K/64, N/64, 9); z==8 -> shared.
__global__ void transpose_cvt9(const float* __restrict__ w, const float* __restrict__ sw,
                               ushort_t* __restrict__ out, int K, int N) {
    __shared__ float t[64][65];
    int z = blockIdx.z;
    const float* in = (z < NEXP) ? w + (size_t)z * K * N : sw;
    out += (size_t)z * K * N;
    int k0 = blockIdx.x * 64, n0 = blockIdx.y * 64;
    int c = threadIdx.x & 63, r4 = threadIdx.x >> 6;
#pragma unroll
    for (int i = 0; i < 16; ++i) {
        int r = r4 + i * 4;
        t[r][c] = in[(size_t)(k0 + r) * N + n0 + c];
    }
    __syncthreads();
#pragma unroll
    for (int i = 0; i < 16; ++i) {
        int r = r4 + i * 4;
        out[(size_t)(n0 + r) * K + k0 + c] = f2b(t[c][r]);
    }
}

// ------------------------------ GEMM (bt) ----------------------------------
// C[M,N] = act(A[M,K] @ Bt[e][N,K]^T + bias), rows grouped by expert
// (256-aligned), expert 8 = shared. 256x256 block, BK=64, 16 waves (1024
// thr, 4x4 wave grid, wave-tile 64x64), XOR-swizzled LDS (pre-swizzled
// source), per-XCD patch swizzle, R8 sync (stage(t+1), vmcnt(4), barriers).
// R11: operands SWAPPED in the MFMA (mfma(B,A)) so each lane's acc holds
// row m = lr, cols n = q4*4 + r (4 consecutive) -> vectorized epilogue:
// uint2 (4x bf16) / float4 stores, float4 bias loads.
template <bool ACT_GELU, bool FFN2>
__global__ __launch_bounds__(1024, 4) void gemm_moe(
    const ushort_t* __restrict__ A, const ushort_t* __restrict__ WtBase,
    const float* __restrict__ bExp, const float* __restrict__ bSh,
    ushort_t* __restrict__ Cb, float* __restrict__ Cf,
    const int* __restrict__ offs, int N, int K) {
    // ---- per-XCD patch swizzle (bijective; NM%4==0, NN%2==0) ----
    int NMt = gridDim.x, NNt = gridDim.y;
    int flat = blockIdx.y * NMt + blockIdx.x;
    int xcd = flat & 7, rank = flat >> 3;
    int PM = NMt >> 2;                    // patch rows (14)
    int PN = NNt >> 1;                    // patch cols (8 or 2)
    int pm = xcd >> 1, pn = xcd & 1;      // 4 x 2 patch grid
    int mi = pm * PM + rank / PN;
    int ni = pn * PN + rank % PN;
    int m0 = mi * 256, n0 = ni * 256;

    int e;
    if (m0 >= SLOT_PAD) {
        e = NEXP;                        // shared region
    } else {
        if (m0 >= offs[NEXP]) return;    // dead pad zone (before any barrier)
        e = 0;
        while (offs[e + 1] <= m0) e++;
    }
    const ushort_t* Bt = WtBase + (size_t)e * N * K;
    const float* bias = (e == NEXP) ? bSh : bExp + (size_t)e * N;

    __shared__ ushort_t As[2][256 * 64];   // 64 KB
    __shared__ ushort_t Bs[2][256 * 64];   // 64 KB

    int tid = threadIdx.x;
    int lane = tid & 63, wid = tid >> 6;   // 16 waves
    int wm = wid >> 2, wn = wid & 3;       // 4 x 4 wave grid
    int q = lane >> 4, lr = lane & 15;

    // staging: per operand 2048 16B-chunks; thread does L = it*1024 + tid.
    // row = L>>3, stored chunk = L&7, source chunk = stored ^ (row&7).
    size_t Aoff[2], Boff[2];
    int ldsOff[2];
#pragma unroll
    for (int it = 0; it < 2; ++it) {
        int L = it * 1024 + tid;
        int row = L >> 3;
        int c = (L & 7) ^ (row & 7);
        Aoff[it] = (size_t)(m0 + row) * K + c * 8;
        Boff[it] = (size_t)(n0 + row) * K + c * 8;
        ldsOff[it] = L * 8;                // ushort elements
    }

    int rowA[4], rowB[4];
#pragma unroll
    for (int i = 0; i < 4; ++i) rowA[i] = wm * 64 + i * 16 + lr;
#pragma unroll
    for (int j = 0; j < 4; ++j) rowB[j] = wn * 64 + j * 16 + lr;

    f32x4 acc[4][4];
#pragma unroll
    for (int i = 0; i < 4; ++i)
#pragma unroll
        for (int j = 0; j < 4; ++j) acc[i][j] = (f32x4)(0.f);

    auto stage = [&](int kb, int buf) {    // 4 loads per thread
#pragma unroll
        for (int it = 0; it < 2; ++it) {
            __builtin_amdgcn_global_load_lds(
                (const __attribute__((address_space(1))) void*)(A + Aoff[it] + kb),
                (__attribute__((address_space(3))) void*)(&As[buf][ldsOff[it]]), 16, 0, 0);
            __builtin_amdgcn_global_load_lds(
                (const __attribute__((address_space(1))) void*)(Bt + Boff[it] + kb),
                (__attribute__((address_space(3))) void*)(&Bs[buf][ldsOff[it]]), 16, 0, 0);
        }
    };
    auto compute = [&](int buf) {
#pragma unroll
        for (int ks = 0; ks < 2; ++ks) {
            bf16x8 af[4], bfr[4];
#pragma unroll
            for (int i = 0; i < 4; ++i) {
                int cA = (ks * 4 + q) ^ (rowA[i] & 7);
                af[i] = *(const bf16x8*)(&As[buf][rowA[i] * 64 + cA * 8]);
            }
#pragma unroll
            for (int j = 0; j < 4; ++j) {
                int cB = (ks * 4 + q) ^ (rowB[j] & 7);
                bfr[j] = *(const bf16x8*)(&Bs[buf][rowB[j] * 64 + cB * 8]);
            }
            // swapped operands: D[n][m] layout -> lane holds row m=lr,
            // cols n = q*4 + r (4 consecutive) per frag
#pragma unroll
            for (int i = 0; i < 4; ++i)
#pragma unroll
                for (int j = 0; j < 4; ++j)
                    acc[i][j] = __builtin_amdgcn_mfma_f32_16x16x32_bf16(
                        bfr[j], af[i], acc[i][j], 0, 0, 0);
        }
    };

    const int nk = K >> 6;
    stage(0, 0);                           // 4 outstanding
    int cur = 0;
    for (int t = 0; t < nk; ++t) {
        if (t + 1 < nk) {
            stage((t + 1) << 6, cur ^ 1);  // 8 outstanding
            asm volatile("s_waitcnt vmcnt(4)" ::: "memory");  // tile t landed
        } else {
            asm volatile("s_waitcnt vmcnt(0)" ::: "memory");
        }
        __builtin_amdgcn_s_barrier();      // all waves see tile t in LDS
        compute(cur);                      // compiler inserts lgkmcnt waits
        __builtin_amdgcn_s_barrier();      // done reading buf before overwrite
        cur ^= 1;
    }

    // epilogue (swapped layout): acc[mi][nj][r] = C[row][colb + nj*16 + r]
    // with row = m0 + wm*64 + mi*16 + lr, colb = n0 + wn*64 + q*4.
    int colb = n0 + wn * 64 + q * 4;
    int rowb = m0 + wm * 64 + lr;
    float4 bz[4];
#pragma unroll
    for (int nj = 0; nj < 4; ++nj)
        bz[nj] = *(const float4*)(bias + colb + nj * 16);
#pragma unroll
    for (int mi = 0; mi < 4; ++mi) {
        int row = rowb + mi * 16;
#pragma unroll
        for (int nj = 0; nj < 4; ++nj) {
            float v0 = acc[mi][nj][0] + bz[nj].x;
            float v1 = acc[mi][nj][1] + bz[nj].y;
            float v2 = acc[mi][nj][2] + bz[nj].z;
            float v3 = acc[mi][nj][3] + bz[nj].w;
            if (ACT_GELU) {
                v0 = gelu_fast(v0); v1 = gelu_fast(v1);
                v2 = gelu_fast(v2); v3 = gelu_fast(v3);
            }
            int col = colb + nj * 16;
            if (!FFN2 || e < NEXP) {
                uint2 u;
                u.x = (unsigned)f2b(v0) | ((unsigned)f2b(v1) << 16);
                u.y = (unsigned)f2b(v2) | ((unsigned)f2b(v3) << 16);
                *(uint2*)(Cb + (size_t)row * N + col) = u;
            } else {
                float4 f = make_float4(v0, v1, v2, v3);
                *(float4*)(Cf + (size_t)(row - SLOT_PAD) * N + col) = f;
            }
        }
    }
}

// ------------------------------- combine -----------------------------------
__global__ void combine_kernel(float* __restrict__ out, const ushort_t* __restrict__ OutS,
                               const int* __restrict__ slot_of, const float* __restrict__ tw) {
    int t = blockIdx.x;
    int d = threadIdx.x * 4;
    int s0 = slot_of[2 * t], s1 = slot_of[2 * t + 1];
    float w0 = tw[2 * t], w1 = tw[2 * t + 1];
    float* po = out + (size_t)t * DDIM + d;
    float4 o = *(float4*)po;
    const ushort_t* p0 = OutS + (size_t)s0 * DDIM + d;
    const ushort_t* p1 = OutS + (size_t)s1 * DDIM + d;
    o.x += w0 * b2f(p0[0]) + w1 * b2f(p1[0]);
    o.y += w0 * b2f(p0[1]) + w1 * b2f(p1[1]);
    o.z += w0 * b2f(p0[2]) + w1 * b2f(p1[2]);
    o.w += w0 * b2f(p0[3]) + w1 * b2f(p1[3]);
    *(float4*)po = o;
}

// ------------------------------- launch ------------------------------------
extern "C" void kernel_launch(void* const* d_in, const int* in_sizes, int n_in,
                              void* d_out, int out_size, void* d_ws, size_t ws_size,
                              hipStream_t stream) {
    const float* x      = (const float*)d_in[0];
    const float* gw     = (const float*)d_in[1];
    const float* w_in   = (const float*)d_in[2];
    const float* b_in   = (const float*)d_in[3];
    const float* w_out  = (const float*)d_in[4];
    const float* b_out  = (const float*)d_in[5];
    const float* sw_in  = (const float*)d_in[6];
    const float* sb_in  = (const float*)d_in[7];
    const float* sw_out = (const float*)d_in[8];
    const float* sb_out = (const float*)d_in[9];
    float* out = (float*)d_out;

    char* ws = (char*)d_ws;
    int*      cnt     = (int*)(ws + OFF_CNT);      // [0..7]=cnt, [8..15]=cur
    int*      offs    = (int*)(ws + OFF_OFFS);
    int*      tidx    = (int*)(ws + OFF_TIDX);
    float*    tw      = (float*)(ws + OFF_TW);
    int*      slot_of = (int*)(ws + OFF_SLOT);
    int*      tok_of  = (int*)(ws + OFF_TOK);
    ushort_t* Xall    = (ushort_t*)(ws + OFF_XALL);
    ushort_t* OutS    = (ushort_t*)(ws + OFF_OUTS); // aliases Xall (used after GEMM1)
    ushort_t* Wt      = (ushort_t*)(ws + OFF_WT);   // [9][N][K], FFN1 then FFN2
    ushort_t* Hbuf    = (ushort_t*)(ws + OFF_H);    // bf16 [14336][4096]

    // routing (cnt+cur zeroed by async memset; no tok_of init needed)
    hipMemsetAsync(cnt, 0, 64, stream);
    gate_kernel<<<T_TOK, 64, 0, stream>>>(x, gw, tidx, tw, cnt);
    assign_kernel<<<(2 * T_TOK + 255) / 256, 256, 0, stream>>>(tidx, cnt, cnt + 8,
                                                               offs, slot_of, tok_of);
    build_x<<<M_ALL, 256, 0, stream>>>(x, tok_of, offs, cnt, Xall);

    // FFN1 weights: [9][4096][1024] bf16 (w_in experts + sw_in as expert 8)
    transpose_cvt9<<<dim3(DDIM / 64, HDIM / 64, NEXP + 1), 256, 0, stream>>>(
        w_in, sw_in, Wt, DDIM, HDIM);
    // H = gelu(Xall @ W1 + b1)
    gemm_moe<true, false><<<dim3(M_ALL / 256, HDIM / 256), 1024, 0, stream>>>(
        Xall, Wt, b_in, sb_in, Hbuf, nullptr, offs, HDIM, DDIM);

    // FFN2 weights: [9][1024][4096] bf16
    transpose_cvt9<<<dim3(HDIM / 64, DDIM / 64, NEXP + 1), 256, 0, stream>>>(
        w_out, sw_out, Wt, HDIM, DDIM);
    // expert rows -> OutS (bf16); shared rows -> out (fp32, includes bias)
    gemm_moe<false, true><<<dim3(M_ALL / 256, DDIM / 256), 1024, 0, stream>>>(
        Hbuf, Wt, b_out, sb_out, OutS, out, offs, DDIM, HDIM);

    // out += w0*OutS[slot0] + w1*OutS[slot1]
    combine_kernel<<<T_TOK, 256, 0, stream>>>(out, OutS, slot_of, tw);
    (void)in_sizes; (void)n_in; (void)out_size; (void)ws_size;
}